// Round 2
// baseline (905.721 us; speedup 1.0000x reference)
//
#include <hip/hip_runtime.h>

#define IN_CH 16
#define OUT_CH 16
#define EDGE_FEAT 32
#define HIDDEN 128
#define WROW 256          // IN_CH*OUT_CH
#define FPB 8             // filters per block in filter-net kernel
#define EPT 4             // edges per thread in edge kernel

// ---------------- Kernel 1: filter net -------------------------------------
__global__ __launch_bounds__(256) void filter_net_kernel(
    const float* __restrict__ ef, const float* __restrict__ W1,
    const float* __restrict__ b1, const float* __restrict__ W2,
    const float* __restrict__ b2, float* __restrict__ weights) {
  __shared__ float ef_s[FPB * EDGE_FEAT];   // 256 floats
  __shared__ float h_s[FPB][HIDDEN];        // 1024 floats
  const int t = threadIdx.x;
  const int f0 = blockIdx.x * FPB;

  ef_s[t] = ef[f0 * EDGE_FEAT + t];
  __syncthreads();

  #pragma unroll
  for (int j = 0; j < (FPB * HIDDEN) / 256; ++j) {
    const int idx = t + j * 256;
    const int fi = idx >> 7;
    const int hi = idx & (HIDDEN - 1);
    float a = b1[hi];
    #pragma unroll
    for (int k = 0; k < EDGE_FEAT; ++k)
      a = fmaf(ef_s[fi * EDGE_FEAT + k], W1[k * HIDDEN + hi], a);
    h_s[fi][hi] = a > 0.f ? a : 0.f;
  }
  __syncthreads();

  float acc[FPB];
  const float bb = b2[t];
  #pragma unroll
  for (int fi = 0; fi < FPB; ++fi) acc[fi] = bb;
  for (int k = 0; k < HIDDEN; ++k) {
    const float w2 = W2[k * WROW + t];
    #pragma unroll
    for (int fi = 0; fi < FPB; ++fi)
      acc[fi] = fmaf(h_s[fi][k], w2, acc[fi]);
  }
  #pragma unroll
  for (int fi = 0; fi < FPB; ++fi)
    weights[(size_t)(f0 + fi) * WROW + t] = acc[fi];
}

// ---------------- Kernel 2: per-edge bmm + segmented atomic reduce ----------
__device__ __forceinline__ void flush_seg(float* __restrict__ sums,
                                          float* __restrict__ deg,
                                          int s, const float4* acc4, float cnt) {
  if (cnt <= 0.f) return;
  float* p = sums + (size_t)s * OUT_CH;
  const float* a = (const float*)acc4;
  #pragma unroll
  for (int c = 0; c < OUT_CH; ++c) atomicAdd(p + c, a[c]);
  atomicAdd(deg + s, cnt);
}

__global__ __launch_bounds__(256) void edge_kernel(
    const float* __restrict__ input, const int* __restrict__ idxn,
    const int* __restrict__ idxe, const int* __restrict__ seg,
    const float* __restrict__ weights, float* __restrict__ sums,
    float* __restrict__ deg, int n_edges) {
  const long base = (long)(blockIdx.x * blockDim.x + threadIdx.x) * EPT;
  if (base >= n_edges) return;
  const long rem = n_edges - base;
  const int nvalid = rem < EPT ? (int)rem : EPT;

  // Preload ALL indices for this thread's edges up front (independent loads).
  int sv[EPT], niv[EPT], fiv[EPT];
  #pragma unroll
  for (int q = 0; q < EPT; ++q) {
    const long e = base + (q < nvalid ? q : nvalid - 1);
    sv[q]  = seg[e];
    niv[q] = idxn[e];
    fiv[q] = idxe[e];
  }

  float4 acc[4];
  #pragma unroll
  for (int j = 0; j < 4; ++j) acc[j] = make_float4(0.f, 0.f, 0.f, 0.f);
  int cur = sv[0];
  float cnt = 0.f;

  #pragma unroll
  for (int q = 0; q < EPT; ++q) {
    if (q >= nvalid) break;

    // Issue x loads (4 independent float4) early.
    const float4* __restrict__ xp =
        (const float4*)(input + (size_t)niv[q] * IN_CH);
    float4 xr[4];
    #pragma unroll
    for (int j = 0; j < 4; ++j) xr[j] = xp[j];

    const float4* __restrict__ wp =
        (const float4*)(weights + (size_t)fiv[q] * WROW);

    if (sv[q] != cur) {
      flush_seg(sums, deg, cur, acc, cnt);
      cur = sv[q];
      cnt = 0.f;
      #pragma unroll
      for (int j = 0; j < 4; ++j) acc[j] = make_float4(0.f, 0.f, 0.f, 0.f);
    }

    const float* xs = (const float*)xr;
    // Stream the 1 KB weight row in 4 chunks of 16 float4 loads each;
    // all 16 loads of a chunk are issued back-to-back (64 VGPR buffer)
    // so ~16 requests are in flight per thread, then 64 FMAs consume them.
    #pragma unroll
    for (int c = 0; c < 4; ++c) {
      float4 w[16];
      #pragma unroll
      for (int u = 0; u < 16; ++u) w[u] = wp[c * 16 + u];
      #pragma unroll
      for (int i2 = 0; i2 < 4; ++i2) {
        const float xi = xs[c * 4 + i2];
        #pragma unroll
        for (int j = 0; j < 4; ++j) {
          const float4 w4 = w[i2 * 4 + j];
          acc[j].x = fmaf(xi, w4.x, acc[j].x);
          acc[j].y = fmaf(xi, w4.y, acc[j].y);
          acc[j].z = fmaf(xi, w4.z, acc[j].z);
          acc[j].w = fmaf(xi, w4.w, acc[j].w);
        }
      }
    }
    cnt += 1.f;
  }
  flush_seg(sums, deg, cur, acc, cnt);
}

// ---------------- Kernel 3: divide by degree --------------------------------
__global__ __launch_bounds__(256) void finalize_kernel(
    const float* __restrict__ sums, const float* __restrict__ deg,
    float* __restrict__ out, int n_nodes) {
  const int n = blockIdx.x * blockDim.x + threadIdx.x;
  if (n >= n_nodes) return;
  const float d = deg[n];
  const float scale = d > 0.f ? 1.f / d : 0.f;
  const float4* sp = (const float4*)(sums + (size_t)n * OUT_CH);
  float4* op = (float4*)(out + (size_t)n * OUT_CH);
  #pragma unroll
  for (int j = 0; j < 4; ++j) {
    float4 v = sp[j];
    v.x *= scale; v.y *= scale; v.z *= scale; v.w *= scale;
    op[j] = v;
  }
}

extern "C" void kernel_launch(void* const* d_in, const int* in_sizes, int n_in,
                              void* d_out, int out_size, void* d_ws, size_t ws_size,
                              hipStream_t stream) {
  const float* input = (const float*)d_in[0];
  const int* idxn    = (const int*)d_in[1];
  const int* idxe    = (const int*)d_in[2];
  const int* seg     = (const int*)d_in[3];
  const float* ef    = (const float*)d_in[4];
  const float* W1    = (const float*)d_in[5];
  const float* b1    = (const float*)d_in[6];
  const float* W2    = (const float*)d_in[7];
  const float* b2    = (const float*)d_in[8];
  float* out = (float*)d_out;

  const int n_nodes   = in_sizes[0] / IN_CH;
  const int n_edges   = in_sizes[1];
  const int n_filters = in_sizes[4] / EDGE_FEAT;

  float* weights = (float*)d_ws;
  float* sums    = weights + (size_t)n_filters * WROW;
  float* deg     = sums + (size_t)n_nodes * OUT_CH;

  hipMemsetAsync(sums, 0,
                 (size_t)(n_nodes * OUT_CH + n_nodes) * sizeof(float), stream);

  filter_net_kernel<<<n_filters / FPB, 256, 0, stream>>>(ef, W1, b1, W2, b2,
                                                         weights);

  const long n_threads = ((long)n_edges + EPT - 1) / EPT;
  edge_kernel<<<(int)((n_threads + 255) / 256), 256, 0, stream>>>(
      input, idxn, idxe, seg, weights, sums, deg, n_edges);

  finalize_kernel<<<(n_nodes + 255) / 256, 256, 0, stream>>>(sums, deg, out,
                                                             n_nodes);
}

// Round 3
// 201.807 us; speedup vs baseline: 4.4880x; 4.4880x over previous
//
#include <hip/hip_runtime.h>

#define IN_CH 16
#define OUT_CH 16
#define EDGE_FEAT 32
#define HIDDEN 128
#define WROW 256          // IN_CH*OUT_CH
#define FPB 8             // filters per block in filter-net kernel

// ---------------- Kernel 1: filter net -------------------------------------
__global__ __launch_bounds__(256) void filter_net_kernel(
    const float* __restrict__ ef, const float* __restrict__ W1,
    const float* __restrict__ b1, const float* __restrict__ W2,
    const float* __restrict__ b2, float* __restrict__ weights) {
  __shared__ float ef_s[FPB * EDGE_FEAT];   // 256 floats
  __shared__ float h_s[FPB][HIDDEN];        // 1024 floats
  const int t = threadIdx.x;
  const int f0 = blockIdx.x * FPB;

  ef_s[t] = ef[f0 * EDGE_FEAT + t];
  __syncthreads();

  #pragma unroll
  for (int j = 0; j < (FPB * HIDDEN) / 256; ++j) {
    const int idx = t + j * 256;
    const int fi = idx >> 7;
    const int hi = idx & (HIDDEN - 1);
    float a = b1[hi];
    #pragma unroll
    for (int k = 0; k < EDGE_FEAT; ++k)
      a = fmaf(ef_s[fi * EDGE_FEAT + k], W1[k * HIDDEN + hi], a);
    h_s[fi][hi] = a > 0.f ? a : 0.f;
  }
  __syncthreads();

  float acc[FPB];
  const float bb = b2[t];
  #pragma unroll
  for (int fi = 0; fi < FPB; ++fi) acc[fi] = bb;
  for (int k = 0; k < HIDDEN; ++k) {
    const float w2 = W2[k * WROW + t];
    #pragma unroll
    for (int fi = 0; fi < FPB; ++fi)
      acc[fi] = fmaf(h_s[fi][k], w2, acc[fi]);
  }
  #pragma unroll
  for (int fi = 0; fi < FPB; ++fi)
    weights[(size_t)(f0 + fi) * WROW + t] = acc[fi];
}

// ---------------- Kernel 2: 4 lanes per edge + wave segmented reduce --------
// Wave layout: lane = e_in_wave*4 + j; 16 edges per wave, lane j owns output
// columns [4j, 4j+4). Weight loads per quad cover one contiguous 64B line.
// seg_ids are sorted -> segmented suffix reduction via shuffles, one atomic
// flush per run per wave.
__global__ __launch_bounds__(256, 4) void edge_kernel(
    const float* __restrict__ input, const int* __restrict__ idxn,
    const int* __restrict__ idxe, const int* __restrict__ seg,
    const float* __restrict__ weights, float* __restrict__ sums,
    float* __restrict__ deg, int n_edges) {
  const int lane = threadIdx.x & 63;
  const int wave_in_block = threadIdx.x >> 6;
  const int e_in_wave = lane >> 2;
  const int j = lane & 3;

  long e = (long)blockIdx.x * 64 + wave_in_block * 16 + e_in_wave;
  const bool valid = e < n_edges;
  if (e >= n_edges) e = n_edges - 1;   // clamp for safe loads

  int s = seg[e];
  const int n = idxn[e];
  const int f = idxe[e];

  // x: 16 floats of the source node (quad lanes share the cacheline).
  const float4* __restrict__ xp = (const float4*)(input + (size_t)n * IN_CH);
  float4 xr[4];
  #pragma unroll
  for (int q = 0; q < 4; ++q) xr[q] = xp[q];
  const float* xs = (const float*)xr;

  // weights: 16 independent float4 loads, kept live in registers.
  const float4* __restrict__ wq = (const float4*)(weights + (size_t)f * WROW);
  float4 wv[16];
  #pragma unroll
  for (int i = 0; i < 16; ++i) wv[i] = wq[i * 4 + j];

  float4 acc = make_float4(0.f, 0.f, 0.f, 0.f);
  #pragma unroll
  for (int i = 0; i < 16; ++i) {
    const float xi = xs[i];
    acc.x = fmaf(xi, wv[i].x, acc.x);
    acc.y = fmaf(xi, wv[i].y, acc.y);
    acc.z = fmaf(xi, wv[i].z, acc.z);
    acc.w = fmaf(xi, wv[i].w, acc.w);
  }
  float cnt = 1.f;
  if (!valid) {
    acc = make_float4(0.f, 0.f, 0.f, 0.f);
    cnt = 0.f;
    s = -1;
  }

  // Segmented suffix sum across edges in the wave (stride 4 keeps j fixed).
  #pragma unroll
  for (int d = 4; d <= 32; d <<= 1) {
    const int src = lane + d;
    const int os = __shfl(s, src & 63);
    const float ox = __shfl(acc.x, src & 63);
    const float oy = __shfl(acc.y, src & 63);
    const float oz = __shfl(acc.z, src & 63);
    const float ow = __shfl(acc.w, src & 63);
    const float oc = __shfl(cnt, src & 63);
    if (src < 64 && os == s) {
      acc.x += ox; acc.y += oy; acc.z += oz; acc.w += ow;
      cnt += oc;
    }
  }

  // Head lane of each run flushes.
  const int ps = __shfl(s, (lane - 4) & 63);
  const bool head = (e_in_wave == 0) || (ps != s);
  if (valid && head && s >= 0) {
    float* p = sums + (size_t)s * OUT_CH + j * 4;
    atomicAdd(p + 0, acc.x);
    atomicAdd(p + 1, acc.y);
    atomicAdd(p + 2, acc.z);
    atomicAdd(p + 3, acc.w);
    if (j == 0) atomicAdd(deg + s, cnt);
  }
}

// ---------------- Kernel 3: divide by degree --------------------------------
__global__ __launch_bounds__(256) void finalize_kernel(
    const float* __restrict__ sums, const float* __restrict__ deg,
    float* __restrict__ out, int n_nodes) {
  const int n = blockIdx.x * blockDim.x + threadIdx.x;
  if (n >= n_nodes) return;
  const float d = deg[n];
  const float scale = d > 0.f ? 1.f / d : 0.f;
  const float4* sp = (const float4*)(sums + (size_t)n * OUT_CH);
  float4* op = (float4*)(out + (size_t)n * OUT_CH);
  #pragma unroll
  for (int q = 0; q < 4; ++q) {
    float4 v = sp[q];
    v.x *= scale; v.y *= scale; v.z *= scale; v.w *= scale;
    op[q] = v;
  }
}

extern "C" void kernel_launch(void* const* d_in, const int* in_sizes, int n_in,
                              void* d_out, int out_size, void* d_ws, size_t ws_size,
                              hipStream_t stream) {
  const float* input = (const float*)d_in[0];
  const int* idxn    = (const int*)d_in[1];
  const int* idxe    = (const int*)d_in[2];
  const int* seg     = (const int*)d_in[3];
  const float* ef    = (const float*)d_in[4];
  const float* W1    = (const float*)d_in[5];
  const float* b1    = (const float*)d_in[6];
  const float* W2    = (const float*)d_in[7];
  const float* b2    = (const float*)d_in[8];
  float* out = (float*)d_out;

  const int n_nodes   = in_sizes[0] / IN_CH;
  const int n_edges   = in_sizes[1];
  const int n_filters = in_sizes[4] / EDGE_FEAT;

  float* weights = (float*)d_ws;
  float* sums    = weights + (size_t)n_filters * WROW;
  float* deg     = sums + (size_t)n_nodes * OUT_CH;

  hipMemsetAsync(sums, 0,
                 (size_t)(n_nodes * OUT_CH + n_nodes) * sizeof(float), stream);

  filter_net_kernel<<<n_filters / FPB, 256, 0, stream>>>(ef, W1, b1, W2, b2,
                                                         weights);

  // 64 edges per 256-thread block (4 lanes per edge).
  const long n_blocks = ((long)n_edges + 63) / 64;
  edge_kernel<<<(int)n_blocks, 256, 0, stream>>>(
      input, idxn, idxe, seg, weights, sums, deg, n_edges);

  finalize_kernel<<<(n_nodes + 255) / 256, 256, 0, stream>>>(sums, deg, out,
                                                             n_nodes);
}

// Round 4
// 168.990 us; speedup vs baseline: 5.3596x; 1.1942x over previous
//
#include <hip/hip_runtime.h>
#include <hip/hip_bf16.h>

#define IN_CH 16
#define OUT_CH 16
#define EDGE_FEAT 32
#define HIDDEN 128
#define WROW 256          // IN_CH*OUT_CH
#define FPB 8             // filters per block in filter-net kernel

// bf16 weight row layout (512 B): 32 chunks of 16 B (8 bf16).
// chunk (u*4 + j), u in [0,8), j in [0,4) holds:
//   [ w[2u][4j+0..3] , w[2u+1][4j+0..3] ]
// so lane j of an edge-quad loads chunks j, 4+j, ..., 28+j (16 B each) and a
// quad's load u covers one contiguous 64 B line.
__device__ __forceinline__ int perm_off(int i, int o) {
  const int u = i >> 1, p = i & 1, j = o >> 2, c = o & 3;
  return (u * 4 + j) * 8 + p * 4 + c;
}

// ---------------- Kernel 1: filter net (bf16 permuted output) ---------------
__global__ __launch_bounds__(256) void filter_net_kernel(
    const float* __restrict__ ef, const float* __restrict__ W1,
    const float* __restrict__ b1, const float* __restrict__ W2,
    const float* __restrict__ b2, __hip_bfloat16* __restrict__ weights) {
  __shared__ float ef_s[FPB * EDGE_FEAT];   // 256 floats
  __shared__ float h_s[FPB][HIDDEN];        // 1024 floats
  const int t = threadIdx.x;
  const int f0 = blockIdx.x * FPB;

  ef_s[t] = ef[f0 * EDGE_FEAT + t];
  __syncthreads();

  #pragma unroll
  for (int j = 0; j < (FPB * HIDDEN) / 256; ++j) {
    const int idx = t + j * 256;
    const int fi = idx >> 7;
    const int hi = idx & (HIDDEN - 1);
    float a = b1[hi];
    #pragma unroll
    for (int k = 0; k < EDGE_FEAT; ++k)
      a = fmaf(ef_s[fi * EDGE_FEAT + k], W1[k * HIDDEN + hi], a);
    h_s[fi][hi] = a > 0.f ? a : 0.f;
  }
  __syncthreads();

  float acc[FPB];
  const float bb = b2[t];
  #pragma unroll
  for (int fi = 0; fi < FPB; ++fi) acc[fi] = bb;
  for (int k = 0; k < HIDDEN; ++k) {
    const float w2 = W2[k * WROW + t];
    #pragma unroll
    for (int fi = 0; fi < FPB; ++fi)
      acc[fi] = fmaf(h_s[fi][k], w2, acc[fi]);
  }
  const int off = perm_off(t >> 4, t & 15);
  #pragma unroll
  for (int fi = 0; fi < FPB; ++fi)
    weights[(size_t)(f0 + fi) * WROW + off] = __float2bfloat16(acc[fi]);
}

// ---------------- Kernel 2: 4 lanes per edge + wave segmented reduce --------
__device__ __forceinline__ float bf_lo(unsigned int v) {
  return __uint_as_float(v << 16);
}
__device__ __forceinline__ float bf_hi(unsigned int v) {
  return __uint_as_float(v & 0xffff0000u);
}

__global__ __launch_bounds__(256, 4) void edge_kernel(
    const float* __restrict__ input, const int* __restrict__ idxn,
    const int* __restrict__ idxe, const int* __restrict__ seg,
    const __hip_bfloat16* __restrict__ weights, float* __restrict__ sums,
    float* __restrict__ deg, int n_edges) {
  const int lane = threadIdx.x & 63;
  const int wave_in_block = threadIdx.x >> 6;
  const int e_in_wave = lane >> 2;
  const int j = lane & 3;

  long e = (long)blockIdx.x * 64 + wave_in_block * 16 + e_in_wave;
  const bool valid = e < n_edges;
  if (e >= n_edges) e = n_edges - 1;   // clamp for safe loads

  int s = seg[e];
  const int n = idxn[e];
  const int f = idxe[e];

  // x: 16 floats of the source node (quad lanes broadcast-share each line).
  const float4* __restrict__ xp = (const float4*)(input + (size_t)n * IN_CH);
  float4 xr[4];
  #pragma unroll
  for (int q = 0; q < 4; ++q) xr[q] = xp[q];
  const float* xs = (const float*)xr;

  // weights: 8 independent 16 B loads (8 bf16 each), quad covers a 64 B line.
  const uint4* __restrict__ wq = (const uint4*)(weights + (size_t)f * WROW);
  uint4 wv[8];
  #pragma unroll
  for (int u = 0; u < 8; ++u) wv[u] = wq[u * 4 + j];

  float4 acc = make_float4(0.f, 0.f, 0.f, 0.f);
  #pragma unroll
  for (int u = 0; u < 8; ++u) {
    const float xi0 = xs[2 * u];
    const float xi1 = xs[2 * u + 1];
    // i = 2u: cols 4j..4j+3 in wv[u].x (c0,c1) and wv[u].y (c2,c3)
    acc.x = fmaf(xi0, bf_lo(wv[u].x), acc.x);
    acc.y = fmaf(xi0, bf_hi(wv[u].x), acc.y);
    acc.z = fmaf(xi0, bf_lo(wv[u].y), acc.z);
    acc.w = fmaf(xi0, bf_hi(wv[u].y), acc.w);
    // i = 2u+1: wv[u].z, wv[u].w
    acc.x = fmaf(xi1, bf_lo(wv[u].z), acc.x);
    acc.y = fmaf(xi1, bf_hi(wv[u].z), acc.y);
    acc.z = fmaf(xi1, bf_lo(wv[u].w), acc.z);
    acc.w = fmaf(xi1, bf_hi(wv[u].w), acc.w);
  }
  float cnt = 1.f;
  if (!valid) {
    acc = make_float4(0.f, 0.f, 0.f, 0.f);
    cnt = 0.f;
    s = -1;
  }

  // Segmented suffix sum across edges in the wave (stride 4 keeps j fixed).
  #pragma unroll
  for (int d = 4; d <= 32; d <<= 1) {
    const int src = lane + d;
    const int os = __shfl(s, src & 63);
    const float ox = __shfl(acc.x, src & 63);
    const float oy = __shfl(acc.y, src & 63);
    const float oz = __shfl(acc.z, src & 63);
    const float ow = __shfl(acc.w, src & 63);
    const float oc = __shfl(cnt, src & 63);
    if (src < 64 && os == s) {
      acc.x += ox; acc.y += oy; acc.z += oz; acc.w += ow;
      cnt += oc;
    }
  }

  // Head lane of each run flushes.
  const int ps = __shfl(s, (lane - 4) & 63);
  const bool head = (e_in_wave == 0) || (ps != s);
  if (valid && head && s >= 0) {
    float* p = sums + (size_t)s * OUT_CH + j * 4;
    atomicAdd(p + 0, acc.x);
    atomicAdd(p + 1, acc.y);
    atomicAdd(p + 2, acc.z);
    atomicAdd(p + 3, acc.w);
    if (j == 0) atomicAdd(deg + s, cnt);
  }
}

// ---------------- Kernel 3: divide by degree --------------------------------
__global__ __launch_bounds__(256) void finalize_kernel(
    const float* __restrict__ sums, const float* __restrict__ deg,
    float* __restrict__ out, int n_nodes) {
  const int n = blockIdx.x * blockDim.x + threadIdx.x;
  if (n >= n_nodes) return;
  const float d = deg[n];
  const float scale = d > 0.f ? 1.f / d : 0.f;
  const float4* sp = (const float4*)(sums + (size_t)n * OUT_CH);
  float4* op = (float4*)(out + (size_t)n * OUT_CH);
  #pragma unroll
  for (int q = 0; q < 4; ++q) {
    float4 v = sp[q];
    v.x *= scale; v.y *= scale; v.z *= scale; v.w *= scale;
    op[q] = v;
  }
}

extern "C" void kernel_launch(void* const* d_in, const int* in_sizes, int n_in,
                              void* d_out, int out_size, void* d_ws, size_t ws_size,
                              hipStream_t stream) {
  const float* input = (const float*)d_in[0];
  const int* idxn    = (const int*)d_in[1];
  const int* idxe    = (const int*)d_in[2];
  const int* seg     = (const int*)d_in[3];
  const float* ef    = (const float*)d_in[4];
  const float* W1    = (const float*)d_in[5];
  const float* b1    = (const float*)d_in[6];
  const float* W2    = (const float*)d_in[7];
  const float* b2    = (const float*)d_in[8];
  float* out = (float*)d_out;

  const int n_nodes   = in_sizes[0] / IN_CH;
  const int n_edges   = in_sizes[1];
  const int n_filters = in_sizes[4] / EDGE_FEAT;

  // workspace: bf16 weights [F*256] (2 MB) | sums [n_nodes*16] | deg [n_nodes]
  __hip_bfloat16* weights = (__hip_bfloat16*)d_ws;
  float* sums = (float*)((char*)d_ws + (size_t)n_filters * WROW * sizeof(__hip_bfloat16));
  float* deg  = sums + (size_t)n_nodes * OUT_CH;

  hipMemsetAsync(sums, 0,
                 (size_t)(n_nodes * OUT_CH + n_nodes) * sizeof(float), stream);

  filter_net_kernel<<<n_filters / FPB, 256, 0, stream>>>(ef, W1, b1, W2, b2,
                                                         weights);

  // 64 edges per 256-thread block (4 lanes per edge).
  const long n_blocks = ((long)n_edges + 63) / 64;
  edge_kernel<<<(int)n_blocks, 256, 0, stream>>>(
      input, idxn, idxe, seg, weights, sums, deg, n_edges);

  finalize_kernel<<<(n_nodes + 255) / 256, 256, 0, stream>>>(sums, deg, out,
                                                             n_nodes);
}

// Round 5
// 165.983 us; speedup vs baseline: 5.4567x; 1.0181x over previous
//
#include <hip/hip_runtime.h>
#include <hip/hip_bf16.h>

#define IN_CH 16
#define OUT_CH 16
#define EDGE_FEAT 32
#define HIDDEN 128
#define WROW 256          // IN_CH*OUT_CH
#define FPB 2             // filters per block in filter-net kernel

// bf16 weight row layout (512 B): 32 chunks of 16 B (8 bf16).
// chunk (u*4 + j), u in [0,8), j in [0,4) holds:
//   [ w[2u][4j+0..3] , w[2u+1][4j+0..3] ]
__device__ __forceinline__ int perm_off(int i, int o) {
  const int u = i >> 1, p = i & 1, j = o >> 2, c = o & 3;
  return (u * 4 + j) * 8 + p * 4 + c;
}

// ---------------- Kernel 1: filter net (bf16 permuted output) ---------------
// FPB=2 -> 2048 blocks = 8 blocks/CU (32 waves/CU) for latency hiding;
// round-4's FPB=8 gave only 2 blocks/CU and stage-2 stalled on L2 latency.
__global__ __launch_bounds__(256) void filter_net_kernel(
    const float* __restrict__ ef, const float* __restrict__ W1,
    const float* __restrict__ b1, const float* __restrict__ W2,
    const float* __restrict__ b2, __hip_bfloat16* __restrict__ weights) {
  __shared__ float ef_s[FPB * EDGE_FEAT];   // 64 floats
  __shared__ float h_s[FPB][HIDDEN];        // 256 floats
  const int t = threadIdx.x;
  const int f0 = blockIdx.x * FPB;

  if (t < FPB * EDGE_FEAT) ef_s[t] = ef[f0 * EDGE_FEAT + t];
  __syncthreads();

  // stage 1: one h value per thread (256 = FPB*HIDDEN exactly).
  {
    const int fi = t >> 7;
    const int hi = t & (HIDDEN - 1);
    float a = b1[hi];
    #pragma unroll
    for (int k = 0; k < EDGE_FEAT; ++k)
      a = fmaf(ef_s[fi * EDGE_FEAT + k], W1[k * HIDDEN + hi], a);
    h_s[fi][hi] = a > 0.f ? a : 0.f;
  }
  __syncthreads();

  // stage 2: thread t owns output column t for both filters.
  float acc0 = b2[t];
  float acc1 = acc0;
  #pragma unroll 4
  for (int k = 0; k < HIDDEN; ++k) {
    const float w2 = W2[k * WROW + t];     // coalesced, independent loads
    acc0 = fmaf(h_s[0][k], w2, acc0);
    acc1 = fmaf(h_s[1][k], w2, acc1);
  }
  const int off = perm_off(t >> 4, t & 15);
  weights[(size_t)(f0 + 0) * WROW + off] = __float2bfloat16(acc0);
  weights[(size_t)(f0 + 1) * WROW + off] = __float2bfloat16(acc1);
}

// ---------------- Kernel 2: 4 lanes per edge + wave segmented reduce --------
__device__ __forceinline__ float bf_lo(unsigned int v) {
  return __uint_as_float(v << 16);
}
__device__ __forceinline__ float bf_hi(unsigned int v) {
  return __uint_as_float(v & 0xffff0000u);
}
// Broadcast lane (quad_base + q)'s value to all 4 lanes of the quad.
template <int Q>
__device__ __forceinline__ float quad_bcast(float v) {
  const int pat = 0x8000 | Q | (Q << 2) | (Q << 4) | (Q << 6);
  return __int_as_float(__builtin_amdgcn_ds_swizzle(__float_as_int(v), pat));
}

__global__ __launch_bounds__(256, 4) void edge_kernel(
    const float* __restrict__ input, const int* __restrict__ idxn,
    const int* __restrict__ idxe, const int* __restrict__ seg,
    const __hip_bfloat16* __restrict__ weights, float* __restrict__ sums,
    float* __restrict__ deg, int n_edges) {
  const int lane = threadIdx.x & 63;
  const int wave_in_block = threadIdx.x >> 6;
  const int e_in_wave = lane >> 2;
  const int j = lane & 3;

  long e = (long)blockIdx.x * 64 + wave_in_block * 16 + e_in_wave;
  const bool valid = e < n_edges;
  if (e >= n_edges) e = n_edges - 1;   // clamp for safe loads

  int s = seg[e];
  const int n = idxn[e];
  const int f = idxe[e];

  // x: lane j loads only its own quarter-row (float4); quad covers the 64 B
  // line exactly once. Full row assembled via quad broadcasts (LDS pipe).
  const float4 xown = ((const float4*)(input + (size_t)n * IN_CH))[j];

  // weights: 8 independent 16 B loads (8 bf16 each), quad covers a 64 B line.
  const uint4* __restrict__ wq = (const uint4*)(weights + (size_t)f * WROW);
  uint4 wv[8];
  #pragma unroll
  for (int u = 0; u < 8; ++u) wv[u] = wq[u * 4 + j];

  float xs[16];
  {
    xs[0]  = quad_bcast<0>(xown.x); xs[1]  = quad_bcast<0>(xown.y);
    xs[2]  = quad_bcast<0>(xown.z); xs[3]  = quad_bcast<0>(xown.w);
    xs[4]  = quad_bcast<1>(xown.x); xs[5]  = quad_bcast<1>(xown.y);
    xs[6]  = quad_bcast<1>(xown.z); xs[7]  = quad_bcast<1>(xown.w);
    xs[8]  = quad_bcast<2>(xown.x); xs[9]  = quad_bcast<2>(xown.y);
    xs[10] = quad_bcast<2>(xown.z); xs[11] = quad_bcast<2>(xown.w);
    xs[12] = quad_bcast<3>(xown.x); xs[13] = quad_bcast<3>(xown.y);
    xs[14] = quad_bcast<3>(xown.z); xs[15] = quad_bcast<3>(xown.w);
  }

  float4 acc = make_float4(0.f, 0.f, 0.f, 0.f);
  #pragma unroll
  for (int u = 0; u < 8; ++u) {
    const float xi0 = xs[2 * u];
    const float xi1 = xs[2 * u + 1];
    acc.x = fmaf(xi0, bf_lo(wv[u].x), acc.x);
    acc.y = fmaf(xi0, bf_hi(wv[u].x), acc.y);
    acc.z = fmaf(xi0, bf_lo(wv[u].y), acc.z);
    acc.w = fmaf(xi0, bf_hi(wv[u].y), acc.w);
    acc.x = fmaf(xi1, bf_lo(wv[u].z), acc.x);
    acc.y = fmaf(xi1, bf_hi(wv[u].z), acc.y);
    acc.z = fmaf(xi1, bf_lo(wv[u].w), acc.z);
    acc.w = fmaf(xi1, bf_hi(wv[u].w), acc.w);
  }
  float cnt = 1.f;
  if (!valid) {
    acc = make_float4(0.f, 0.f, 0.f, 0.f);
    cnt = 0.f;
    s = -1;
  }

  // Segmented suffix sum across edges in the wave (stride 4 keeps j fixed).
  #pragma unroll
  for (int d = 4; d <= 32; d <<= 1) {
    const int src = lane + d;
    const int os = __shfl(s, src & 63);
    const float ox = __shfl(acc.x, src & 63);
    const float oy = __shfl(acc.y, src & 63);
    const float oz = __shfl(acc.z, src & 63);
    const float ow = __shfl(acc.w, src & 63);
    const float oc = __shfl(cnt, src & 63);
    if (src < 64 && os == s) {
      acc.x += ox; acc.y += oy; acc.z += oz; acc.w += ow;
      cnt += oc;
    }
  }

  // Head lane of each run flushes.
  const int ps = __shfl(s, (lane - 4) & 63);
  const bool head = (e_in_wave == 0) || (ps != s);
  if (valid && head && s >= 0) {
    float* p = sums + (size_t)s * OUT_CH + j * 4;
    atomicAdd(p + 0, acc.x);
    atomicAdd(p + 1, acc.y);
    atomicAdd(p + 2, acc.z);
    atomicAdd(p + 3, acc.w);
    if (j == 0) atomicAdd(deg + s, cnt);
  }
}

// ---------------- Kernel 3: divide by degree --------------------------------
__global__ __launch_bounds__(256) void finalize_kernel(
    const float* __restrict__ sums, const float* __restrict__ deg,
    float* __restrict__ out, int n_nodes) {
  const int n = blockIdx.x * blockDim.x + threadIdx.x;
  if (n >= n_nodes) return;
  const float d = deg[n];
  const float scale = d > 0.f ? 1.f / d : 0.f;
  const float4* sp = (const float4*)(sums + (size_t)n * OUT_CH);
  float4* op = (float4*)(out + (size_t)n * OUT_CH);
  #pragma unroll
  for (int q = 0; q < 4; ++q) {
    float4 v = sp[q];
    v.x *= scale; v.y *= scale; v.z *= scale; v.w *= scale;
    op[q] = v;
  }
}

extern "C" void kernel_launch(void* const* d_in, const int* in_sizes, int n_in,
                              void* d_out, int out_size, void* d_ws, size_t ws_size,
                              hipStream_t stream) {
  const float* input = (const float*)d_in[0];
  const int* idxn    = (const int*)d_in[1];
  const int* idxe    = (const int*)d_in[2];
  const int* seg     = (const int*)d_in[3];
  const float* ef    = (const float*)d_in[4];
  const float* W1    = (const float*)d_in[5];
  const float* b1    = (const float*)d_in[6];
  const float* W2    = (const float*)d_in[7];
  const float* b2    = (const float*)d_in[8];
  float* out = (float*)d_out;

  const int n_nodes   = in_sizes[0] / IN_CH;
  const int n_edges   = in_sizes[1];
  const int n_filters = in_sizes[4] / EDGE_FEAT;

  // workspace: bf16 weights [F*256] (2 MB) | sums [n_nodes*16] | deg [n_nodes]
  __hip_bfloat16* weights = (__hip_bfloat16*)d_ws;
  float* sums = (float*)((char*)d_ws + (size_t)n_filters * WROW * sizeof(__hip_bfloat16));
  float* deg  = sums + (size_t)n_nodes * OUT_CH;

  hipMemsetAsync(sums, 0,
                 (size_t)(n_nodes * OUT_CH + n_nodes) * sizeof(float), stream);

  filter_net_kernel<<<n_filters / FPB, 256, 0, stream>>>(ef, W1, b1, W2, b2,
                                                         weights);

  // 64 edges per 256-thread block (4 lanes per edge).
  const long n_blocks = ((long)n_edges + 63) / 64;
  edge_kernel<<<(int)n_blocks, 256, 0, stream>>>(
      input, idxn, idxe, seg, weights, sums, deg, n_edges);

  finalize_kernel<<<(n_nodes + 255) / 256, 256, 0, stream>>>(sums, deg, out,
                                                             n_nodes);
}

// Round 6
// 165.364 us; speedup vs baseline: 5.4771x; 1.0037x over previous
//
#include <hip/hip_runtime.h>
#include <hip/hip_bf16.h>

#define IN_CH 16
#define OUT_CH 16
#define EDGE_FEAT 32
#define HIDDEN 128
#define WROW 256          // IN_CH*OUT_CH
#define FN_FPB 4          // filters per block in filter-net kernel

// bf16 weight row layout (512 B): 32 chunks of 16 B (8 bf16).
// chunk (u*4 + j), u in [0,8), j in [0,4) holds:
//   [ w[2u][4j+0..3] , w[2u+1][4j+0..3] ]
// Edge-kernel lane j of a quad loads chunks {u*4+j}, so a quad's load u is
// one contiguous 64 B line.

__device__ __forceinline__ unsigned short f2bf(float v) {
  __hip_bfloat16 h = __float2bfloat16(v);
  return *(unsigned short*)&h;
}

// ---------------- Kernel 1: filter net (reg-tiled GEMM + fused zeroing) -----
// Grid: F/4 = 1024 blocks. Thread (fslot = t>>6, cq = t&63) computes filter
// f0+fslot, output cols [4cq, 4cq+4). Stage-2 inner: 1 float4 load + 4 FMA
// per k (vs round-5's 1 dword load + 2 FMA). Also zeroes sums|deg up front.
__global__ __launch_bounds__(256) void filter_net_kernel(
    const float* __restrict__ ef, const float* __restrict__ W1,
    const float* __restrict__ b1, const float* __restrict__ W2,
    const float* __restrict__ b2, __hip_bfloat16* __restrict__ weights,
    float* __restrict__ zero_base, int nzero4) {
  const int t = threadIdx.x;
  const int f0 = blockIdx.x * FN_FPB;

  // fused zeroing of sums+deg (3.4 MB spread over 1024 blocks)
  {
    const int gid = blockIdx.x * 256 + t;
    if (gid < nzero4)
      ((float4*)zero_base)[gid] = make_float4(0.f, 0.f, 0.f, 0.f);
  }

  __shared__ float ef_s[FN_FPB * EDGE_FEAT];  // 128 floats
  __shared__ float h_s[FN_FPB][HIDDEN];       // 512 floats
  if (t < FN_FPB * EDGE_FEAT) ef_s[t] = ef[f0 * EDGE_FEAT + t];
  __syncthreads();

  // stage 1: 512 h values, 2 per thread.
  #pragma unroll
  for (int r = 0; r < 2; ++r) {
    const int idx = t + r * 256;
    const int fi = idx >> 7;
    const int hi = idx & (HIDDEN - 1);
    float a = b1[hi];
    #pragma unroll
    for (int k = 0; k < EDGE_FEAT; ++k)
      a = fmaf(ef_s[fi * EDGE_FEAT + k], W1[k * HIDDEN + hi], a);
    h_s[fi][hi] = a > 0.f ? a : 0.f;
  }
  __syncthreads();

  const int fslot = t >> 6;
  const int cq = t & 63;

  float4 acc;
  acc.x = b2[4 * cq + 0];
  acc.y = b2[4 * cq + 1];
  acc.z = b2[4 * cq + 2];
  acc.w = b2[4 * cq + 3];
  const float* __restrict__ hrow = h_s[fslot];
  #pragma unroll 8
  for (int k = 0; k < HIDDEN; ++k) {
    const float4 w = ((const float4*)(W2 + (size_t)k * WROW))[cq];
    const float hv = hrow[k];
    acc.x = fmaf(hv, w.x, acc.x);
    acc.y = fmaf(hv, w.y, acc.y);
    acc.z = fmaf(hv, w.z, acc.z);
    acc.w = fmaf(hv, w.w, acc.w);
  }

  // epilogue: cols 4cq..4cq+3 -> permuted chunk, packed 8 B store.
  const int i = cq >> 2;       // in-channel
  const int jo = cq & 3;       // out-channel quad
  const int u = i >> 1, p = i & 1;
  const int off = (u * 4 + jo) * 8 + p * 4;   // element offset in row
  uint2 st;
  st.x = (unsigned)f2bf(acc.x) | ((unsigned)f2bf(acc.y) << 16);
  st.y = (unsigned)f2bf(acc.z) | ((unsigned)f2bf(acc.w) << 16);
  *(uint2*)(weights + (size_t)(f0 + fslot) * WROW + off) = st;
}

// ---------------- Kernel 2: 4 lanes/edge, 2 groups/wave, seg reduce ---------
__device__ __forceinline__ float bf_lo(unsigned int v) {
  return __uint_as_float(v << 16);
}
__device__ __forceinline__ float bf_hi(unsigned int v) {
  return __uint_as_float(v & 0xffff0000u);
}
template <int Q>
__device__ __forceinline__ float quad_bcast(float v) {
  const int pat = 0x8000 | Q | (Q << 2) | (Q << 4) | (Q << 6);
  return __int_as_float(__builtin_amdgcn_ds_swizzle(__float_as_int(v), pat));
}

__device__ __forceinline__ float4 edge_dot(const float4 xo, const uint4* wv) {
  float xs[16];
  xs[0]  = quad_bcast<0>(xo.x); xs[1]  = quad_bcast<0>(xo.y);
  xs[2]  = quad_bcast<0>(xo.z); xs[3]  = quad_bcast<0>(xo.w);
  xs[4]  = quad_bcast<1>(xo.x); xs[5]  = quad_bcast<1>(xo.y);
  xs[6]  = quad_bcast<1>(xo.z); xs[7]  = quad_bcast<1>(xo.w);
  xs[8]  = quad_bcast<2>(xo.x); xs[9]  = quad_bcast<2>(xo.y);
  xs[10] = quad_bcast<2>(xo.z); xs[11] = quad_bcast<2>(xo.w);
  xs[12] = quad_bcast<3>(xo.x); xs[13] = quad_bcast<3>(xo.y);
  xs[14] = quad_bcast<3>(xo.z); xs[15] = quad_bcast<3>(xo.w);
  float4 acc = make_float4(0.f, 0.f, 0.f, 0.f);
  #pragma unroll
  for (int u = 0; u < 8; ++u) {
    const float xi0 = xs[2 * u];
    const float xi1 = xs[2 * u + 1];
    acc.x = fmaf(xi0, bf_lo(wv[u].x), acc.x);
    acc.y = fmaf(xi0, bf_hi(wv[u].x), acc.y);
    acc.z = fmaf(xi0, bf_lo(wv[u].y), acc.z);
    acc.w = fmaf(xi0, bf_hi(wv[u].y), acc.w);
    acc.x = fmaf(xi1, bf_lo(wv[u].z), acc.x);
    acc.y = fmaf(xi1, bf_hi(wv[u].z), acc.y);
    acc.z = fmaf(xi1, bf_lo(wv[u].w), acc.z);
    acc.w = fmaf(xi1, bf_hi(wv[u].w), acc.w);
  }
  return acc;
}

// Segmented suffix reduce over the 16 edges of one group; head lanes flush.
__device__ __forceinline__ void seg_reduce_flush(
    int s, float4 acc, float cnt, bool valid, int lane, int e_in_wave, int j,
    float* __restrict__ sums, float* __restrict__ deg) {
  if (!valid) {
    acc = make_float4(0.f, 0.f, 0.f, 0.f);
    cnt = 0.f;
    s = -1;
  }
  #pragma unroll
  for (int d = 4; d <= 32; d <<= 1) {
    const int src = lane + d;
    const int os = __shfl(s, src & 63);
    const float ox = __shfl(acc.x, src & 63);
    const float oy = __shfl(acc.y, src & 63);
    const float oz = __shfl(acc.z, src & 63);
    const float ow = __shfl(acc.w, src & 63);
    const float oc = __shfl(cnt, src & 63);
    if (src < 64 && os == s) {
      acc.x += ox; acc.y += oy; acc.z += oz; acc.w += ow;
      cnt += oc;
    }
  }
  const int ps = __shfl(s, (lane - 4) & 63);
  const bool head = (e_in_wave == 0) || (ps != s);
  if (valid && head && s >= 0) {
    float* p = sums + (size_t)s * OUT_CH + j * 4;
    atomicAdd(p + 0, acc.x);
    atomicAdd(p + 1, acc.y);
    atomicAdd(p + 2, acc.z);
    atomicAdd(p + 3, acc.w);
    if (j == 0) atomicAdd(deg + s, cnt);
  }
}

__global__ __launch_bounds__(256, 4) void edge_kernel(
    const float* __restrict__ input, const int* __restrict__ idxn,
    const int* __restrict__ idxe, const int* __restrict__ seg,
    const __hip_bfloat16* __restrict__ weights, float* __restrict__ sums,
    float* __restrict__ deg, int n_edges) {
  const int lane = threadIdx.x & 63;
  const int wib = threadIdx.x >> 6;
  const int e_in_wave = lane >> 2;
  const int j = lane & 3;

  const long wbase = (long)blockIdx.x * 128 + wib * 32;
  long eA = wbase + e_in_wave;
  long eB = eA + 16;
  const bool vA = eA < n_edges;
  const bool vB = eB < n_edges;
  if (!vA) eA = n_edges - 1;
  if (!vB) eB = n_edges - 1;

  const int sA = seg[eA];
  const int nA = idxn[eA];
  const int fA = idxe[eA];
  const int sB = seg[eB];
  const int nB = idxn[eB];
  const int fB = idxe[eB];

  // Issue ALL 18 vector loads before any compute/flush (~2x lines in flight).
  const float4 xoA = ((const float4*)(input + (size_t)nA * IN_CH))[j];
  const uint4* __restrict__ wqA = (const uint4*)(weights + (size_t)fA * WROW);
  uint4 wvA[8];
  #pragma unroll
  for (int u = 0; u < 8; ++u) wvA[u] = wqA[u * 4 + j];
  const float4 xoB = ((const float4*)(input + (size_t)nB * IN_CH))[j];
  const uint4* __restrict__ wqB = (const uint4*)(weights + (size_t)fB * WROW);
  uint4 wvB[8];
  #pragma unroll
  for (int u = 0; u < 8; ++u) wvB[u] = wqB[u * 4 + j];

  const float4 accA = edge_dot(xoA, wvA);
  const float4 accB = edge_dot(xoB, wvB);

  seg_reduce_flush(sA, accA, 1.f, vA, lane, e_in_wave, j, sums, deg);
  seg_reduce_flush(sB, accB, 1.f, vB, lane, e_in_wave, j, sums, deg);
}

// ---------------- Kernel 3: divide by degree --------------------------------
__global__ __launch_bounds__(256) void finalize_kernel(
    const float* __restrict__ sums, const float* __restrict__ deg,
    float* __restrict__ out, int n_nodes) {
  const int n = blockIdx.x * blockDim.x + threadIdx.x;
  if (n >= n_nodes) return;
  const float d = deg[n];
  const float scale = d > 0.f ? 1.f / d : 0.f;
  const float4* sp = (const float4*)(sums + (size_t)n * OUT_CH);
  float4* op = (float4*)(out + (size_t)n * OUT_CH);
  #pragma unroll
  for (int q = 0; q < 4; ++q) {
    float4 v = sp[q];
    v.x *= scale; v.y *= scale; v.z *= scale; v.w *= scale;
    op[q] = v;
  }
}

extern "C" void kernel_launch(void* const* d_in, const int* in_sizes, int n_in,
                              void* d_out, int out_size, void* d_ws, size_t ws_size,
                              hipStream_t stream) {
  const float* input = (const float*)d_in[0];
  const int* idxn    = (const int*)d_in[1];
  const int* idxe    = (const int*)d_in[2];
  const int* seg     = (const int*)d_in[3];
  const float* ef    = (const float*)d_in[4];
  const float* W1    = (const float*)d_in[5];
  const float* b1    = (const float*)d_in[6];
  const float* W2    = (const float*)d_in[7];
  const float* b2    = (const float*)d_in[8];
  float* out = (float*)d_out;

  const int n_nodes   = in_sizes[0] / IN_CH;
  const int n_edges   = in_sizes[1];
  const int n_filters = in_sizes[4] / EDGE_FEAT;

  // workspace: bf16 weights [F*256] (2 MB) | sums [n_nodes*16] | deg [n_nodes]
  __hip_bfloat16* weights = (__hip_bfloat16*)d_ws;
  float* sums = (float*)((char*)d_ws + (size_t)n_filters * WROW * sizeof(__hip_bfloat16));
  float* deg  = sums + (size_t)n_nodes * OUT_CH;

  // filter_net also zeroes sums|deg (contiguous region, float4-aligned).
  const int nzero4 = (n_nodes * (OUT_CH + 1)) / 4;
  filter_net_kernel<<<n_filters / FN_FPB, 256, 0, stream>>>(
      ef, W1, b1, W2, b2, weights, sums, nzero4);

  // 128 edges per 256-thread block (4 lanes/edge, 2 groups of 16 per wave).
  const long n_blocks = ((long)n_edges + 127) / 128;
  edge_kernel<<<(int)n_blocks, 256, 0, stream>>>(
      input, idxn, idxe, seg, weights, sums, deg, n_edges);

  finalize_kernel<<<(n_nodes + 255) / 256, 256, 0, stream>>>(sums, deg, out,
                                                             n_nodes);
}

// Round 8
// 160.633 us; speedup vs baseline: 5.6385x; 1.0295x over previous
//
#include <hip/hip_runtime.h>
#include <hip/hip_bf16.h>

#define IN_CH 16
#define OUT_CH 16
#define EDGE_FEAT 32
#define HIDDEN 128
#define WROW 256          // IN_CH*OUT_CH
#define FN_FPB 8          // filters per block in filter-net kernel

// f16 weight row layout (512 B): 32 chunks of 16 B.
// chunk (u*4 + j), u in [0,8), j in [0,4): dword c (c in [0,4)) holds the
// f16 pair ( w[2u][4j+c] , w[2u+1][4j+c] ) — pairs run along the input
// channel so one v_dot2_f32_f16 consumes both.
// Edge-quad lane j loads chunks {u*4+j}; a quad's load u is one 64 B line.

typedef __fp16 half2_v __attribute__((ext_vector_type(2)));

__device__ __forceinline__ unsigned pk_f16(float lo, float hi) {
  half2_v h = __builtin_amdgcn_cvt_pkrtz(lo, hi);
  return __builtin_bit_cast(unsigned, h);
}

__device__ __forceinline__ float dot2(unsigned wpair, half2_v xp, float acc) {
  half2_v w = __builtin_bit_cast(half2_v, wpair);
#if __has_builtin(__builtin_amdgcn_fdot2)
  return __builtin_amdgcn_fdot2(xp, w, acc, false);
#else
  acc = fmaf((float)xp[0], (float)w[0], acc);
  return fmaf((float)xp[1], (float)w[1], acc);
#endif
}

// ---------------- Kernel 1: filter net (f16 pair-layout output) -------------
// 8 filters/block; thread (fslot=t>>5, u=(t&31)>>2, jo=t&3) computes the
// 8 outputs {out[2u][4jo+c], out[2u+1][4jo+c]} so the f16 pair store is local.
__global__ __launch_bounds__(256) void filter_net_kernel(
    const float* __restrict__ ef, const float* __restrict__ W1,
    const float* __restrict__ b1, const float* __restrict__ W2,
    const float* __restrict__ b2, unsigned short* __restrict__ weights,
    float* __restrict__ zero_base, int nzero4) {
  const int t = threadIdx.x;
  const int f0 = blockIdx.x * FN_FPB;

  // fused zeroing of sums+deg
  for (int gid = blockIdx.x * 256 + t; gid < nzero4; gid += gridDim.x * 256)
    ((float4*)zero_base)[gid] = make_float4(0.f, 0.f, 0.f, 0.f);

  __shared__ float ef_s[FN_FPB * EDGE_FEAT];  // 256 floats
  __shared__ float h_s[FN_FPB][HIDDEN];       // 1024 floats
  ef_s[t] = ef[f0 * EDGE_FEAT + t];
  __syncthreads();

  // stage 1: 1024 h values, 4 per thread.
  #pragma unroll
  for (int r = 0; r < 4; ++r) {
    const int idx = t + r * 256;
    const int fi = idx >> 7;
    const int hi = idx & (HIDDEN - 1);
    float a = b1[hi];
    #pragma unroll
    for (int k = 0; k < EDGE_FEAT; ++k)
      a = fmaf(ef_s[fi * EDGE_FEAT + k], W1[k * HIDDEN + hi], a);
    h_s[fi][hi] = a > 0.f ? a : 0.f;
  }
  __syncthreads();

  const int fslot = t >> 5;
  const int combo = t & 31;
  const int u = combo >> 2;
  const int jo = combo & 3;
  const int colLo = 32 * u + 4 * jo;   // out col base for i = 2u
  const int colHi = colLo + 16;        // for i = 2u+1

  float4 aLo = *(const float4*)(b2 + colLo);
  float4 aHi = *(const float4*)(b2 + colHi);
  const float* __restrict__ hrow = h_s[fslot];
  #pragma unroll 4
  for (int k = 0; k < HIDDEN; ++k) {
    const float4 wLo = *(const float4*)(W2 + (size_t)k * WROW + colLo);
    const float4 wHi = *(const float4*)(W2 + (size_t)k * WROW + colHi);
    const float hv = hrow[k];
    aLo.x = fmaf(hv, wLo.x, aLo.x);
    aLo.y = fmaf(hv, wLo.y, aLo.y);
    aLo.z = fmaf(hv, wLo.z, aLo.z);
    aLo.w = fmaf(hv, wLo.w, aLo.w);
    aHi.x = fmaf(hv, wHi.x, aHi.x);
    aHi.y = fmaf(hv, wHi.y, aHi.y);
    aHi.z = fmaf(hv, wHi.z, aHi.z);
    aHi.w = fmaf(hv, wHi.w, aHi.w);
  }

  uint4 st;
  st.x = pk_f16(aLo.x, aHi.x);
  st.y = pk_f16(aLo.y, aHi.y);
  st.z = pk_f16(aLo.z, aHi.z);
  st.w = pk_f16(aLo.w, aHi.w);
  *(uint4*)(weights + (size_t)(f0 + fslot) * WROW + (u * 4 + jo) * 8) = st;
}

// ---------------- Kernel 2: 4 lanes/edge, 2 groups/wave, dot2 inner ---------
template <int Q>
__device__ __forceinline__ int quad_bcast_i(int v) {
  const int pat = 0x8000 | Q | (Q << 2) | (Q << 4) | (Q << 6);
  return __builtin_amdgcn_ds_swizzle(v, pat);
}

__device__ __forceinline__ float4 edge_dot(const float4 xo, const uint4* wv) {
  // pack own 4 x values into 2 f16 pairs, then broadcast pairs across quad.
  const int p0 = (int)pk_f16(xo.x, xo.y);
  const int p1 = (int)pk_f16(xo.z, xo.w);
  half2_v xp[8];
  xp[0] = __builtin_bit_cast(half2_v, quad_bcast_i<0>(p0));
  xp[1] = __builtin_bit_cast(half2_v, quad_bcast_i<0>(p1));
  xp[2] = __builtin_bit_cast(half2_v, quad_bcast_i<1>(p0));
  xp[3] = __builtin_bit_cast(half2_v, quad_bcast_i<1>(p1));
  xp[4] = __builtin_bit_cast(half2_v, quad_bcast_i<2>(p0));
  xp[5] = __builtin_bit_cast(half2_v, quad_bcast_i<2>(p1));
  xp[6] = __builtin_bit_cast(half2_v, quad_bcast_i<3>(p0));
  xp[7] = __builtin_bit_cast(half2_v, quad_bcast_i<3>(p1));

  float4 acc = make_float4(0.f, 0.f, 0.f, 0.f);
  #pragma unroll
  for (int u = 0; u < 8; ++u) {
    acc.x = dot2(wv[u].x, xp[u], acc.x);
    acc.y = dot2(wv[u].y, xp[u], acc.y);
    acc.z = dot2(wv[u].z, xp[u], acc.z);
    acc.w = dot2(wv[u].w, xp[u], acc.w);
  }
  return acc;
}

__device__ __forceinline__ void seg_reduce_flush(
    int s, float4 acc, float cnt, bool valid, int lane, int e_in_wave, int j,
    float* __restrict__ sums, float* __restrict__ deg) {
  if (!valid) {
    acc = make_float4(0.f, 0.f, 0.f, 0.f);
    cnt = 0.f;
    s = -1;
  }
  #pragma unroll
  for (int d = 4; d <= 32; d <<= 1) {
    const int src = lane + d;
    const int os = __shfl(s, src & 63);
    const float ox = __shfl(acc.x, src & 63);
    const float oy = __shfl(acc.y, src & 63);
    const float oz = __shfl(acc.z, src & 63);
    const float ow = __shfl(acc.w, src & 63);
    const float oc = __shfl(cnt, src & 63);
    if (src < 64 && os == s) {
      acc.x += ox; acc.y += oy; acc.z += oz; acc.w += ow;
      cnt += oc;
    }
  }
  const int ps = __shfl(s, (lane - 4) & 63);
  const bool head = (e_in_wave == 0) || (ps != s);
  if (valid && head && s >= 0) {
    float* p = sums + (size_t)s * OUT_CH + j * 4;
    atomicAdd(p + 0, acc.x);
    atomicAdd(p + 1, acc.y);
    atomicAdd(p + 2, acc.z);
    atomicAdd(p + 3, acc.w);
    if (j == 0) atomicAdd(deg + s, cnt);
  }
}

__global__ __launch_bounds__(256, 4) void edge_kernel(
    const float* __restrict__ input, const int* __restrict__ idxn,
    const int* __restrict__ idxe, const int* __restrict__ seg,
    const unsigned short* __restrict__ weights, float* __restrict__ sums,
    float* __restrict__ deg, int n_edges) {
  const int lane = threadIdx.x & 63;
  const int wib = threadIdx.x >> 6;
  const int e_in_wave = lane >> 2;
  const int j = lane & 3;

  const long wbase = (long)blockIdx.x * 128 + wib * 32;
  long eA = wbase + e_in_wave;
  long eB = eA + 16;
  const bool vA = eA < n_edges;
  const bool vB = eB < n_edges;
  if (!vA) eA = n_edges - 1;
  if (!vB) eB = n_edges - 1;

  const int sA = seg[eA];
  const int nA = idxn[eA];
  const int fA = idxe[eA];
  const int sB = seg[eB];
  const int nB = idxn[eB];
  const int fB = idxe[eB];

  // Issue ALL 18 vector loads before any compute/flush.
  const float4 xoA = ((const float4*)(input + (size_t)nA * IN_CH))[j];
  const uint4* __restrict__ wqA = (const uint4*)(weights + (size_t)fA * WROW);
  uint4 wvA[8];
  #pragma unroll
  for (int u = 0; u < 8; ++u) wvA[u] = wqA[u * 4 + j];
  const float4 xoB = ((const float4*)(input + (size_t)nB * IN_CH))[j];
  const uint4* __restrict__ wqB = (const uint4*)(weights + (size_t)fB * WROW);
  uint4 wvB[8];
  #pragma unroll
  for (int u = 0; u < 8; ++u) wvB[u] = wqB[u * 4 + j];

  const float4 accA = edge_dot(xoA, wvA);
  const float4 accB = edge_dot(xoB, wvB);

  seg_reduce_flush(sA, accA, 1.f, vA, lane, e_in_wave, j, sums, deg);
  seg_reduce_flush(sB, accB, 1.f, vB, lane, e_in_wave, j, sums, deg);
}

// ---------------- Kernel 3: divide by degree --------------------------------
__global__ __launch_bounds__(256) void finalize_kernel(
    const float* __restrict__ sums, const float* __restrict__ deg,
    float* __restrict__ out, int n_nodes) {
  const int n = blockIdx.x * blockDim.x + threadIdx.x;
  if (n >= n_nodes) return;
  const float d = deg[n];
  const float scale = d > 0.f ? 1.f / d : 0.f;
  const float4* sp = (const float4*)(sums + (size_t)n * OUT_CH);
  float4* op = (float4*)(out + (size_t)n * OUT_CH);
  #pragma unroll
  for (int q = 0; q < 4; ++q) {
    float4 v = sp[q];
    v.x *= scale; v.y *= scale; v.z *= scale; v.w *= scale;
    op[q] = v;
  }
}

extern "C" void kernel_launch(void* const* d_in, const int* in_sizes, int n_in,
                              void* d_out, int out_size, void* d_ws, size_t ws_size,
                              hipStream_t stream) {
  const float* input = (const float*)d_in[0];
  const int* idxn    = (const int*)d_in[1];
  const int* idxe    = (const int*)d_in[2];
  const int* seg     = (const int*)d_in[3];
  const float* ef    = (const float*)d_in[4];
  const float* W1    = (const float*)d_in[5];
  const float* b1    = (const float*)d_in[6];
  const float* W2    = (const float*)d_in[7];
  const float* b2    = (const float*)d_in[8];
  float* out = (float*)d_out;

  const int n_nodes   = in_sizes[0] / IN_CH;
  const int n_edges   = in_sizes[1];
  const int n_filters = in_sizes[4] / EDGE_FEAT;

  // workspace: f16 weights [F*256] (2 MB) | sums [n_nodes*16] | deg [n_nodes]
  unsigned short* weights = (unsigned short*)d_ws;
  float* sums = (float*)((char*)d_ws + (size_t)n_filters * WROW * sizeof(unsigned short));
  float* deg  = sums + (size_t)n_nodes * OUT_CH;

  // filter_net also zeroes sums|deg (contiguous region, float4-aligned).
  const int nzero4 = (n_nodes * (OUT_CH + 1)) / 4;
  filter_net_kernel<<<n_filters / FN_FPB, 256, 0, stream>>>(
      ef, W1, b1, W2, b2, weights, sums, nzero4);

  // 128 edges per 256-thread block (4 lanes/edge, 2 groups of 16 per wave).
  const long n_blocks = ((long)n_edges + 127) / 128;
  edge_kernel<<<(int)n_blocks, 256, 0, stream>>>(
      input, idxn, idxe, seg, weights, sums, deg, n_edges);

  finalize_kernel<<<(n_nodes + 255) / 256, 256, 0, stream>>>(sums, deg, out,
                                                             n_nodes);
}